// Round 1
// baseline (304.743 us; speedup 1.0000x reference)
//
#include <hip/hip_runtime.h>
#include <math.h>

#define B_ 64
#define L_ 512
#define N_ 321
#define P_ 720
#define E_ 8
#define R_ 32
#define CID_ 32
#define H_ 64
#define ER_ 256  // E_*R_

// workspace layout (float offsets)
#define OFF_MEAN   0
#define OFF_SDEV   (B_*N_)                 // 20544
#define OFF_GATE   (2*B_*N_)               // 41088
#define OFF_CS1    (OFF_GATE + N_*E_)      // 43656
#define OFF_BIASGT (OFF_CS1 + ER_)         // 43912
#define OFF_W1F    (OFF_BIASGT + P_*N_)    // 275032
#define OFF_HG     (OFF_W1F + L_*ER_)      // 406104
// total floats: 406104 + 64*256*321 = 5,665,368  (~22.7 MB)

// ---------------- router: gate[n,e] = softmax(relu(ident@rw1+rb1)@rw2+rb2) ----
__global__ void router_kernel(const float* __restrict__ ident,
                              const float* __restrict__ rw1, const float* __restrict__ rb1,
                              const float* __restrict__ rw2, const float* __restrict__ rb2,
                              float* __restrict__ gate) {
    int n = blockIdx.x;
    int t = threadIdx.x;  // 0..63
    __shared__ float hid[H_];
    __shared__ float lg[E_];
    float acc = rb1[t];
    #pragma unroll
    for (int c = 0; c < CID_; ++c)
        acc = fmaf(ident[n*CID_ + c], rw1[c*H_ + t], acc);
    hid[t] = fmaxf(acc, 0.f);
    __syncthreads();
    if (t < E_) {
        float a = rb2[t];
        #pragma unroll
        for (int h = 0; h < H_; ++h) a = fmaf(hid[h], rw2[h*E_ + t], a);
        lg[t] = a;
    }
    __syncthreads();
    if (t == 0) {
        float m = lg[0];
        #pragma unroll
        for (int e = 1; e < E_; ++e) m = fmaxf(m, lg[e]);
        float s = 0.f, ex[E_];
        #pragma unroll
        for (int e = 0; e < E_; ++e) { ex[e] = expf(lg[e] - m); s += ex[e]; }
        float inv = 1.f / s;
        #pragma unroll
        for (int e = 0; e < E_; ++e) gate[n*E_ + e] = ex[e] * inv;
    }
}

// ---------------- repack w1 [E,L,R] -> w1f [L, E*R] -------------------------
__global__ void w1f_kernel(const float* __restrict__ w1, float* __restrict__ w1f) {
    int l = blockIdx.x;
    int er = threadIdx.x;            // 0..255
    int e = er >> 5, r = er & 31;
    w1f[l*ER_ + er] = w1[e*(L_*R_) + l*R_ + r];
}

// ---------------- cs1[er] = sum_l w1f[l,er] ---------------------------------
__global__ void cs1_kernel(const float* __restrict__ w1f, float* __restrict__ cs1) {
    int er = threadIdx.x;
    float s = 0.f;
    for (int l = 0; l < L_; ++l) s += w1f[l*ER_ + er];
    cs1[er] = s;
}

// ---------------- biasgT[p,n] = sum_e gate[n,e]*b[e,p] ----------------------
__global__ void biasg_kernel(const float* __restrict__ gate, const float* __restrict__ b,
                             float* __restrict__ biasgT) {
    int n = blockIdx.x*256 + threadIdx.x;
    int p = blockIdx.y;
    if (n >= N_) return;
    float acc = 0.f;
    #pragma unroll
    for (int e = 0; e < E_; ++e) acc = fmaf(gate[n*E_ + e], b[e*P_ + p], acc);
    biasgT[p*N_ + n] = acc;
}

// ---------------- per-(b,n) mean / std (ddof=1) -----------------------------
__global__ void stats_kernel(const float* __restrict__ x,
                             float* __restrict__ meanv, float* __restrict__ sdev) {
    int b = blockIdx.x;
    int nl = threadIdx.x & 63;
    int q  = threadIdx.x >> 6;   // 0..3
    int n = blockIdx.y*64 + nl;
    float s1 = 0.f, s2 = 0.f;
    if (n < N_) {
        const float* xp = x + (size_t)b*L_*N_ + n;
        for (int l = q; l < L_; l += 4) {
            float v = xp[(size_t)l*N_];
            s1 += v; s2 = fmaf(v, v, s2);
        }
    }
    __shared__ float a1[4][64], a2[4][64];
    a1[q][nl] = s1; a2[q][nl] = s2;
    __syncthreads();
    if (q == 0 && n < N_) {
        s1 = a1[0][nl] + a1[1][nl] + a1[2][nl] + a1[3][nl];
        s2 = a2[0][nl] + a2[1][nl] + a2[2][nl] + a2[3][nl];
        float mean = s1 * (1.f/L_);
        float var = (s2 - L_*mean*mean) * (1.f/(L_-1));
        var = fmaxf(var, 0.f);
        meanv[b*N_ + n] = mean;
        sdev[b*N_ + n]  = sqrtf(var) + 1e-6f;
    }
}

// ---------------- GEMM1: hg[b,er,n] = gate[n,e]*(sum_l w1f[l,er]*x[b,l,n] - mean*cs1[er])
__global__ __launch_bounds__(256) void gemm1_kernel(
        const float* __restrict__ x, const float* __restrict__ w1f,
        const float* __restrict__ gate, const float* __restrict__ cs1,
        const float* __restrict__ meanv, float* __restrict__ hg) {
    const int m0 = blockIdx.x * 64;     // er
    const int n0 = blockIdx.y * 64;     // n
    const int b  = blockIdx.z;
    const float* Bmat = x + (size_t)b*L_*N_;
    __shared__ float As[16][64];
    __shared__ float Bs[16][64];
    int tid = threadIdx.x;
    int tx = tid & 15, ty = tid >> 4;
    int arow = tid >> 4;                // 0..15
    int acol = (tid & 15) * 4;          // 0,4,..60
    int bcol = tid & 63;
    int bq   = tid >> 6;                // 0..3
    float acc[4][4] = {};

    for (int k0 = 0; k0 < L_; k0 += 16) {
        *reinterpret_cast<float4*>(&As[arow][acol]) =
            *reinterpret_cast<const float4*>(&w1f[(size_t)(k0+arow)*ER_ + m0 + acol]);
        #pragma unroll
        for (int j = 0; j < 4; ++j) {
            int r = bq*4 + j;
            int n = n0 + bcol;
            Bs[r][bcol] = (n < N_) ? Bmat[(size_t)(k0+r)*N_ + n] : 0.f;
        }
        __syncthreads();
        #pragma unroll
        for (int k = 0; k < 16; ++k) {
            float4 a4 = *reinterpret_cast<const float4*>(&As[k][ty*4]);
            float4 b4 = *reinterpret_cast<const float4*>(&Bs[k][tx*4]);
            float ar[4] = {a4.x, a4.y, a4.z, a4.w};
            float br[4] = {b4.x, b4.y, b4.z, b4.w};
            #pragma unroll
            for (int i = 0; i < 4; ++i)
                #pragma unroll
                for (int j = 0; j < 4; ++j)
                    acc[i][j] = fmaf(ar[i], br[j], acc[i][j]);
        }
        __syncthreads();
    }

    // epilogue
    float mj[4]; int nj[4];
    #pragma unroll
    for (int j = 0; j < 4; ++j) {
        nj[j] = n0 + tx*4 + j;
        mj[j] = (nj[j] < N_) ? meanv[b*N_ + nj[j]] : 0.f;
    }
    #pragma unroll
    for (int i = 0; i < 4; ++i) {
        int m = m0 + ty*4 + i;
        int e = m >> 5;
        float cs = cs1[m];
        float* hp = hg + ((size_t)b*ER_ + m)*N_;
        #pragma unroll
        for (int j = 0; j < 4; ++j) {
            if (nj[j] < N_) {
                float val = gate[nj[j]*E_ + e] * (acc[i][j] - mj[j]*cs);
                hp[nj[j]] = val;
            }
        }
    }
}

// ---------------- GEMM2: out[b,p,n] = sum_er w2[er,p]*hg[b,er,n] + biasgT[p,n]*std + mean
__global__ __launch_bounds__(256) void gemm2_kernel(
        const float* __restrict__ hg, const float* __restrict__ w2,
        const float* __restrict__ biasgT, const float* __restrict__ meanv,
        const float* __restrict__ sdev, float* __restrict__ out) {
    const int m0 = blockIdx.x * 64;     // p
    const int n0 = blockIdx.y * 64;     // n
    const int b  = blockIdx.z;
    const float* Bmat = hg + (size_t)b*ER_*N_;
    __shared__ float As[16][64];
    __shared__ float Bs[16][64];
    int tid = threadIdx.x;
    int tx = tid & 15, ty = tid >> 4;
    int arow = tid >> 4;
    int acol = (tid & 15) * 4;
    int bcol = tid & 63;
    int bq   = tid >> 6;
    float acc[4][4] = {};

    for (int k0 = 0; k0 < ER_; k0 += 16) {
        float4 av = make_float4(0.f, 0.f, 0.f, 0.f);
        if (m0 + acol < P_)
            av = *reinterpret_cast<const float4*>(&w2[(size_t)(k0+arow)*P_ + m0 + acol]);
        *reinterpret_cast<float4*>(&As[arow][acol]) = av;
        #pragma unroll
        for (int j = 0; j < 4; ++j) {
            int r = bq*4 + j;
            int n = n0 + bcol;
            Bs[r][bcol] = (n < N_) ? Bmat[(size_t)(k0+r)*N_ + n] : 0.f;
        }
        __syncthreads();
        #pragma unroll
        for (int k = 0; k < 16; ++k) {
            float4 a4 = *reinterpret_cast<const float4*>(&As[k][ty*4]);
            float4 b4 = *reinterpret_cast<const float4*>(&Bs[k][tx*4]);
            float ar[4] = {a4.x, a4.y, a4.z, a4.w};
            float br[4] = {b4.x, b4.y, b4.z, b4.w};
            #pragma unroll
            for (int i = 0; i < 4; ++i)
                #pragma unroll
                for (int j = 0; j < 4; ++j)
                    acc[i][j] = fmaf(ar[i], br[j], acc[i][j]);
        }
        __syncthreads();
    }

    float mj[4], sj[4]; int nj[4];
    #pragma unroll
    for (int j = 0; j < 4; ++j) {
        nj[j] = n0 + tx*4 + j;
        int bn = b*N_ + ((nj[j] < N_) ? nj[j] : 0);
        mj[j] = meanv[bn];
        sj[j] = sdev[bn];
    }
    #pragma unroll
    for (int i = 0; i < 4; ++i) {
        int p = m0 + ty*4 + i;
        if (p < P_) {
            float* op = out + ((size_t)b*P_ + p)*N_;
            const float* bg = biasgT + (size_t)p*N_;
            #pragma unroll
            for (int j = 0; j < 4; ++j) {
                if (nj[j] < N_) {
                    op[nj[j]] = acc[i][j] + bg[nj[j]]*sj[j] + mj[j];
                }
            }
        }
    }
}

extern "C" void kernel_launch(void* const* d_in, const int* in_sizes, int n_in,
                              void* d_out, int out_size, void* d_ws, size_t ws_size,
                              hipStream_t stream) {
    const float* x     = (const float*)d_in[0];
    const float* ident = (const float*)d_in[1];
    const float* rw1   = (const float*)d_in[2];
    const float* rb1   = (const float*)d_in[3];
    const float* rw2   = (const float*)d_in[4];
    const float* rb2   = (const float*)d_in[5];
    const float* w1    = (const float*)d_in[6];
    const float* w2    = (const float*)d_in[7];
    const float* bias  = (const float*)d_in[8];
    float* out = (float*)d_out;
    float* ws  = (float*)d_ws;

    float* meanv  = ws + OFF_MEAN;
    float* sdev   = ws + OFF_SDEV;
    float* gate   = ws + OFF_GATE;
    float* cs1    = ws + OFF_CS1;
    float* biasgT = ws + OFF_BIASGT;
    float* w1f    = ws + OFF_W1F;
    float* hg     = ws + OFF_HG;

    router_kernel<<<N_, 64, 0, stream>>>(ident, rw1, rb1, rw2, rb2, gate);
    w1f_kernel<<<L_, 256, 0, stream>>>(w1, w1f);
    cs1_kernel<<<1, 256, 0, stream>>>(w1f, cs1);
    biasg_kernel<<<dim3(2, P_), 256, 0, stream>>>(gate, bias, biasgT);
    stats_kernel<<<dim3(B_, (N_+63)/64), 256, 0, stream>>>(x, meanv, sdev);
    gemm1_kernel<<<dim3(ER_/64, (N_+63)/64, B_), 256, 0, stream>>>(x, w1f, gate, cs1, meanv, hg);
    gemm2_kernel<<<dim3((P_+63)/64, (N_+63)/64, B_), 256, 0, stream>>>(hg, w2, biasgT, meanv, sdev, out);
}

// Round 2
// 95.297 us; speedup vs baseline: 3.1978x; 3.1978x over previous
//
#include <hip/hip_runtime.h>
#include <math.h>

#define B_ 64
#define L_ 512
#define N_ 321
#define P_ 720
#define E_ 8
#define R_ 32
#define CID_ 32
#define H_ 64
#define ER_ 256

typedef __attribute__((ext_vector_type(8))) short bf16x8;
typedef __attribute__((ext_vector_type(4))) float f32x4;
typedef __attribute__((ext_vector_type(8))) unsigned short u16x8;
typedef __attribute__((ext_vector_type(4))) unsigned short u16x4;

// workspace layout (float offsets)
#define OFF_MEAN 0
#define OFF_SDEV (B_*N_)                    // 20544
#define OFF_GATE (2*B_*N_)                  // 41088
#define OFF_CS1  (OFF_GATE + N_*E_)         // 43656
#define OFF_W1K  (OFF_CS1 + ER_)            // 43912  (bf16: 256*512 elems = 65536 floats)
#define OFF_W2T  (OFF_W1K + ER_*L_/2)       // 109448 (bf16: 720*256 elems = 92160 floats)
#define OFF_HG   (OFF_W2T + P_*ER_/2)       // 201608 (bf16: 64*321*256 = 2629632 floats)
// total ~2.83M floats = 11.3 MB

__device__ __forceinline__ unsigned short f2bf(float f) {
    unsigned u = __float_as_uint(f);
    u += 0x7fffu + ((u >> 16) & 1u);
    return (unsigned short)(u >> 16);
}
__device__ __forceinline__ float bf2f(unsigned short h) {
    return __uint_as_float(((unsigned)h) << 16);
}

// ---------------- router ----------------------------------------------------
__global__ void router_kernel(const float* __restrict__ ident,
                              const float* __restrict__ rw1, const float* __restrict__ rb1,
                              const float* __restrict__ rw2, const float* __restrict__ rb2,
                              float* __restrict__ gate) {
    int n = blockIdx.x;
    int t = threadIdx.x;  // 0..63
    __shared__ float hid[H_];
    __shared__ float lg[E_];
    float acc = rb1[t];
    #pragma unroll
    for (int c = 0; c < CID_; ++c)
        acc = fmaf(ident[n*CID_ + c], rw1[c*H_ + t], acc);
    hid[t] = fmaxf(acc, 0.f);
    __syncthreads();
    if (t < E_) {
        float a = rb2[t];
        #pragma unroll
        for (int h = 0; h < H_; ++h) a = fmaf(hid[h], rw2[h*E_ + t], a);
        lg[t] = a;
    }
    __syncthreads();
    if (t == 0) {
        float m = lg[0];
        #pragma unroll
        for (int e = 1; e < E_; ++e) m = fmaxf(m, lg[e]);
        float s = 0.f, ex[E_];
        #pragma unroll
        for (int e = 0; e < E_; ++e) { ex[e] = expf(lg[e] - m); s += ex[e]; }
        float inv = 1.f / s;
        #pragma unroll
        for (int e = 0; e < E_; ++e) gate[n*E_ + e] = ex[e] * inv;
    }
}

// ---------------- prep: w1k [er][l] bf16, w2T [p][er] bf16, cs1 -------------
__global__ void prep_kernel(const float* __restrict__ w1, const float* __restrict__ w2,
                            unsigned short* __restrict__ w1k, unsigned short* __restrict__ w2t,
                            float* __restrict__ cs1) {
    int bid = blockIdx.x, t = threadIdx.x;
    if (bid < 512) {                 // w1k: 256*512 elems
        int g = bid*256 + t;
        int er = g >> 9, l = g & 511;
        float v = w1[(size_t)(er >> 5)*(L_*R_) + (size_t)l*R_ + (er & 31)];
        w1k[g] = f2bf(v);
    } else if (bid < 512 + 720) {    // w2T: 720*256 elems
        int g = (bid - 512)*256 + t;
        int p = g >> 8, er = g & 255;
        w2t[g] = f2bf(w2[(size_t)er*P_ + p]);
    } else {                         // cs1[er] = sum_l bf16(w1[e,l,r])
        int er = t;
        int e = er >> 5, r = er & 31;
        float s = 0.f;
        for (int l = 0; l < L_; ++l)
            s += bf2f(f2bf(w1[(size_t)e*(L_*R_) + (size_t)l*R_ + r]));
        cs1[er] = s;
    }
}

// ---------------- GEMM1: hg[b][n][er] = gate[n,e]*(sum_l w1k[er,l]*x[b,l,n] - mean*cs1)
// also computes mean/std (fused stats). BM=256(er, full), BN=64(n), BK=32, K=512.
__global__ __launch_bounds__(512) void gemm1_kernel(
        const float* __restrict__ x, const unsigned short* __restrict__ w1k,
        const float* __restrict__ gate, const float* __restrict__ cs1,
        float* __restrict__ meanv, float* __restrict__ sdev,
        unsigned short* __restrict__ hg) {
    const int n0 = blockIdx.x * 64;
    const int b  = blockIdx.y;
    const int tid = threadIdx.x;
    const int lane = tid & 63;
    const int wave = tid >> 6;       // 0..7
    const int wm = wave >> 1;        // er-base = wm*64
    const int wn = wave & 1;         // n-base = wn*32

    __shared__ unsigned short As[256][40];   // er x k, row stride 80B (20 dw, gcd4)
    __shared__ unsigned short Bs[64][40];    // n x k
    __shared__ float red1[8][64];
    __shared__ float red2[8][64];
    __shared__ float gateS[64][8];
    __shared__ float cs1S[256];
    __shared__ float meanS[64];

    if (tid < 256) cs1S[tid] = cs1[tid];
    {
        int row = tid >> 3, e = tid & 7;
        int n = n0 + row;
        gateS[row][e] = (n < N_) ? gate[n*E_ + e] : 0.f;
    }

    const int arow = tid >> 1;          // 0..255
    const int acol = (tid & 1) * 16;    // 0/16
    const int xn = tid & 63;            // local n (one column per thread)
    const int xkb = (tid >> 6) * 4;     // k sub-base 0..28

    float s1 = 0.f, s2 = 0.f;
    f32x4 acc[4][2];
    #pragma unroll
    for (int i = 0; i < 4; ++i)
        #pragma unroll
        for (int j = 0; j < 2; ++j) acc[i][j] = (f32x4){0.f,0.f,0.f,0.f};

    const float* xb = x + (size_t)b * L_ * N_;
    const int nglob = n0 + xn;
    const bool nvalid = (nglob < N_);

    for (int k0 = 0; k0 < L_; k0 += 32) {
        // global loads (regs)
        u16x8 a0 = *(const u16x8*)&w1k[(size_t)arow*L_ + k0 + acol];
        u16x8 a1 = *(const u16x8*)&w1k[(size_t)arow*L_ + k0 + acol + 8];
        float xv[4];
        #pragma unroll
        for (int i = 0; i < 4; ++i)
            xv[i] = nvalid ? xb[(size_t)(k0 + xkb + i)*N_ + nglob] : 0.f;
        __syncthreads();   // previous iteration's reads complete
        *(u16x8*)&As[arow][acol]   = a0;
        *(u16x8*)&As[arow][acol+8] = a1;
        u16x4 bp;
        #pragma unroll
        for (int i = 0; i < 4; ++i) {
            float v = xv[i];
            s1 += v;
            s2 = fmaf(v, v, s2);
            bp[i] = f2bf(v);
        }
        *(u16x4*)&Bs[xn][xkb] = bp;
        __syncthreads();
        // MFMA
        bf16x8 af[4], bfr[2];
        #pragma unroll
        for (int fm = 0; fm < 4; ++fm)
            af[fm] = *(const bf16x8*)&As[wm*64 + fm*16 + (lane & 15)][(lane >> 4)*8];
        #pragma unroll
        for (int fn = 0; fn < 2; ++fn)
            bfr[fn] = *(const bf16x8*)&Bs[wn*32 + fn*16 + (lane & 15)][(lane >> 4)*8];
        #pragma unroll
        for (int fm = 0; fm < 4; ++fm)
            #pragma unroll
            for (int fn = 0; fn < 2; ++fn)
                acc[fm][fn] = __builtin_amdgcn_mfma_f32_16x16x32_bf16(af[fm], bfr[fn], acc[fm][fn], 0, 0, 0);
    }

    // fused stats: reduce 8 k-slices per column
    red1[tid >> 6][xn] = s1;
    red2[tid >> 6][xn] = s2;
    __syncthreads();
    if (tid < 64) {
        float a = 0.f, q = 0.f;
        #pragma unroll
        for (int kk = 0; kk < 8; ++kk) { a += red1[kk][tid]; q += red2[kk][tid]; }
        float mean = a * (1.f/L_);
        float var = (q - (float)L_*mean*mean) * (1.f/(L_-1));
        var = fmaxf(var, 0.f);
        float sd = sqrtf(var) + 1e-6f;
        meanS[tid] = mean;
        int n = n0 + tid;
        if (n < N_) { meanv[b*N_ + n] = mean; sdev[b*N_ + n] = sd; }
    }
    __syncthreads();

    // epilogue: hg[b][n][er] bf16
    #pragma unroll
    for (int fm = 0; fm < 4; ++fm) {
        int er0 = wm*64 + fm*16 + (lane >> 4)*4;
        int e = er0 >> 5;
        #pragma unroll
        for (int fn = 0; fn < 2; ++fn) {
            int nl = wn*32 + fn*16 + (lane & 15);
            int n = n0 + nl;
            if (n < N_) {
                float g = gateS[nl][e];
                float m = meanS[nl];
                u16x4 pk;
                #pragma unroll
                for (int j = 0; j < 4; ++j) {
                    float v = g * (acc[fm][fn][j] - m * cs1S[er0 + j]);
                    pk[j] = f2bf(v);
                }
                *(u16x4*)&hg[((size_t)b*N_ + n)*ER_ + er0] = pk;
            }
        }
    }
}

// ---------------- GEMM2: out[b][p][n] = sum_er w2T[p,er]*hg[b,n,er] + (sum_e gate*b)*std + mean
// BM=128(p), BN=64(n), BK=64, K=256.
__global__ __launch_bounds__(512) void gemm2_kernel(
        const unsigned short* __restrict__ hg, const unsigned short* __restrict__ w2t,
        const float* __restrict__ gate, const float* __restrict__ bias,
        const float* __restrict__ meanv, const float* __restrict__ sdev,
        float* __restrict__ out) {
    const int p0 = blockIdx.x * 128;
    const int n0 = blockIdx.y * 64;
    const int b  = blockIdx.z;
    const int tid = threadIdx.x;
    const int lane = tid & 63;
    const int wave = tid >> 6;
    const int wm = wave >> 1;    // p-base = wm*32
    const int wn = wave & 1;     // n-base = wn*32

    __shared__ unsigned short As[128][72];   // p x er, stride 144B (36 dw, gcd4)
    __shared__ unsigned short Bs[64][72];    // n x er
    __shared__ float gateS[64][8];
    __shared__ float biasS[8][128];
    __shared__ float meanS[64], stdS[64];

    {
        int row = tid >> 3, e = tid & 7;
        int n = n0 + row;
        gateS[row][e] = (n < N_) ? gate[n*E_ + e] : 0.f;
    }
    #pragma unroll
    for (int r = 0; r < 2; ++r) {
        int idx = tid + r*512;
        int e = idx >> 7, pp = idx & 127;
        int p = p0 + pp;
        biasS[e][pp] = (p < P_) ? bias[e*P_ + p] : 0.f;
    }
    if (tid < 64) {
        int n = n0 + tid;
        meanS[tid] = (n < N_) ? meanv[b*N_ + n] : 0.f;
        stdS[tid]  = (n < N_) ? sdev[b*N_ + n] : 0.f;
    }

    const int ar = tid >> 2, ac = (tid & 3) * 16;   // A: 128 rows x 64, 32B/thread
    const int br = tid >> 3, bc = (tid & 7) * 8;    // B: 64 rows x 64, 16B/thread
    const unsigned short* hgb = hg + (size_t)b * N_ * ER_;

    f32x4 acc[2][2];
    #pragma unroll
    for (int i = 0; i < 2; ++i)
        #pragma unroll
        for (int j = 0; j < 2; ++j) acc[i][j] = (f32x4){0.f,0.f,0.f,0.f};

    for (int k0 = 0; k0 < ER_; k0 += 64) {
        u16x8 a0 = {0,0,0,0,0,0,0,0}, a1 = {0,0,0,0,0,0,0,0}, bv = {0,0,0,0,0,0,0,0};
        if (p0 + ar < P_) {
            a0 = *(const u16x8*)&w2t[(size_t)(p0 + ar)*ER_ + k0 + ac];
            a1 = *(const u16x8*)&w2t[(size_t)(p0 + ar)*ER_ + k0 + ac + 8];
        }
        if (n0 + br < N_)
            bv = *(const u16x8*)&hgb[(size_t)(n0 + br)*ER_ + k0 + bc];
        __syncthreads();
        *(u16x8*)&As[ar][ac]   = a0;
        *(u16x8*)&As[ar][ac+8] = a1;
        *(u16x8*)&Bs[br][bc]   = bv;
        __syncthreads();
        #pragma unroll
        for (int kc = 0; kc < 2; ++kc) {
            bf16x8 af[2], bfr[2];
            #pragma unroll
            for (int fm = 0; fm < 2; ++fm)
                af[fm] = *(const bf16x8*)&As[wm*32 + fm*16 + (lane & 15)][kc*32 + (lane >> 4)*8];
            #pragma unroll
            for (int fn = 0; fn < 2; ++fn)
                bfr[fn] = *(const bf16x8*)&Bs[wn*32 + fn*16 + (lane & 15)][kc*32 + (lane >> 4)*8];
            #pragma unroll
            for (int fm = 0; fm < 2; ++fm)
                #pragma unroll
                for (int fn = 0; fn < 2; ++fn)
                    acc[fm][fn] = __builtin_amdgcn_mfma_f32_16x16x32_bf16(af[fm], bfr[fn], acc[fm][fn], 0, 0, 0);
        }
    }

    // epilogue
    #pragma unroll
    for (int fm = 0; fm < 2; ++fm) {
        int pb = p0 + wm*32 + fm*16 + (lane >> 4)*4;
        #pragma unroll
        for (int fn = 0; fn < 2; ++fn) {
            int nl = wn*32 + fn*16 + (lane & 15);
            int n = n0 + nl;
            if (n < N_) {
                float mean = meanS[nl], sd = stdS[nl];
                #pragma unroll
                for (int j = 0; j < 4; ++j) {
                    int p = pb + j;
                    if (p < P_) {
                        float bg = 0.f;
                        #pragma unroll
                        for (int e = 0; e < E_; ++e)
                            bg = fmaf(gateS[nl][e], biasS[e][p - p0], bg);
                        out[((size_t)b*P_ + p)*N_ + n] = acc[fm][fn][j] + bg*sd + mean;
                    }
                }
            }
        }
    }
}

extern "C" void kernel_launch(void* const* d_in, const int* in_sizes, int n_in,
                              void* d_out, int out_size, void* d_ws, size_t ws_size,
                              hipStream_t stream) {
    const float* x     = (const float*)d_in[0];
    const float* ident = (const float*)d_in[1];
    const float* rw1   = (const float*)d_in[2];
    const float* rb1   = (const float*)d_in[3];
    const float* rw2   = (const float*)d_in[4];
    const float* rb2   = (const float*)d_in[5];
    const float* w1    = (const float*)d_in[6];
    const float* w2    = (const float*)d_in[7];
    const float* bias  = (const float*)d_in[8];
    float* out = (float*)d_out;
    float* ws  = (float*)d_ws;

    float* meanv = ws + OFF_MEAN;
    float* sdev  = ws + OFF_SDEV;
    float* gate  = ws + OFF_GATE;
    float* cs1   = ws + OFF_CS1;
    unsigned short* w1k = (unsigned short*)(ws + OFF_W1K);
    unsigned short* w2t = (unsigned short*)(ws + OFF_W2T);
    unsigned short* hg  = (unsigned short*)(ws + OFF_HG);

    router_kernel<<<N_, 64, 0, stream>>>(ident, rw1, rb1, rw2, rb2, gate);
    prep_kernel<<<512 + 720 + 1, 256, 0, stream>>>(w1, w2, w1k, w2t, cs1);
    gemm1_kernel<<<dim3(6, B_), 512, 0, stream>>>(x, w1k, gate, cs1, meanv, sdev, hg);
    gemm2_kernel<<<dim3(6, 6, B_), 512, 0, stream>>>(hg, w2t, gate, bias, meanv, sdev, out);
}